// Round 2
// baseline (105.195 us; speedup 1.0000x reference)
//
#include <hip/hip_runtime.h>

#define BB 2
#define CC 3
#define TT 8
#define HW 448
#define AA 32
#define GG 14      // 448/32
#define RR 11      // 11x11 region grid
#define NR 121
#define NKEY 4
#define NS 500
#define NCH 25     // chunks per bk
#define SPC 20     // samples per chunk (25*20 = 500)
#define XSH (GG * HW)  // 6272 floats per a1-half

typedef unsigned short u16;
typedef unsigned int u32;
typedef float f32x4 __attribute__((ext_vector_type(4)));

__device__ __forceinline__ float bf2f(u16 u) {
  union { u32 i; float f; } v; v.i = ((u32)u) << 16; return v.f;
}
__device__ __forceinline__ u16 f2bf(float f) {
  union { float f; u32 i; } v; v.f = f;
  u32 u = v.i;
  return (u16)((u + 0x7fffu + ((u >> 16) & 1u)) >> 16);  // round-nearest-even
}

// dtype sniff (validated round 3): score ~ U(0,1); bf16 bit patterns of such
// values lie in {0} U [0x2000, 0x3F80]; f32 mantissa halves are random.
__device__ __forceinline__ bool sniff_is_f32(const void* scorev) {
  const u16* sh16 = (const u16*)scorev;
  bool bf_ok = true;
#pragma unroll
  for (int i = 0; i < 16; i++) {
    const u16 v = sh16[i];
    if (!(v == 0 || (v >= 0x2000 && v <= 0x3F80))) bf_ok = false;
  }
  return !bf_ok;
}

__device__ __forceinline__ float read_sigma(const void* sigmav, bool is_f32) {
  const u32 w0 = *(const u32*)sigmav;
  if (is_f32) { union { u32 i; float f; } v; v.i = w0; return v.f; }
  float sg = bf2f((u16)(w0 & 0xffffu));
  union { u32 i; float f; } v; v.i = w0;
  if (!(sg > -100.f && sg < 100.f) && (v.f > -100.f && v.f < 100.f)) sg = v.f;
  return sg;
}

// -------- Kernel 1: partial histograms, one block per (bk, chunk) -----------
// 200 blocks x 128 threads. Unchanged (validated; ~2-3 us total).
__global__ __launch_bounds__(128) void hist_part(
    const void* __restrict__ scorev, const void* __restrict__ noisev,
    const void* __restrict__ sigmav, int* __restrict__ wsp) {
  const int bk = blockIdx.x / NCH;
  const int ch = blockIdx.x % NCH;
  const int tid = threadIdx.x;

  __shared__ float nl[SPC * NR];  // 9680 B
  __shared__ float scn[NR];
  __shared__ int hist[NR];
  __shared__ float lohi[2];

  const bool is_f32 = sniff_is_f32(scorev);
  const float sg = read_sigma(sigmav, is_f32);

  const size_t chunk_elem = (size_t)(bk * NS + ch * SPC) * NR;

  // stage noise chunk -> LDS (f32)
  if (is_f32) {
    const float* nb = (const float*)noisev + chunk_elem;
    for (int i = tid; i < SPC * NR; i += 128) nl[i] = nb[i];
  } else {
    const u16* nb = (const u16*)noisev + chunk_elem;
    for (int i = tid; i < SPC * NR; i += 128) nl[i] = bf2f(nb[i]);
  }

  // pooled 4x4-mean score -> scn
  if (tid < NR) {
    hist[tid] = 0;
    const int oi = tid / RR, oj = tid - oi * RR;
    float ssum = 0.f;
    if (is_f32) {
      const float* sp = (const float*)scorev + bk * (GG * GG);
#pragma unroll
      for (int ki = 0; ki < 4; ki++)
#pragma unroll
        for (int kj = 0; kj < 4; kj++) ssum += sp[(oi + ki) * GG + (oj + kj)];
    } else {
      const u16* sp = (const u16*)scorev + bk * (GG * GG);
#pragma unroll
      for (int ki = 0; ki < 4; ki++)
#pragma unroll
        for (int kj = 0; kj < 4; kj++) ssum += bf2f(sp[(oi + ki) * GG + (oj + kj)]);
    }
    scn[tid] = ssum * 0.0625f;
  }
  __syncthreads();
  if (tid < 64) {
    float v1 = scn[tid];
    float v2 = (tid + 64 < NR) ? scn[tid + 64] : v1;
    float mn = fminf(v1, v2), mx = fmaxf(v1, v2);
#pragma unroll
    for (int off = 32; off > 0; off >>= 1) {
      mn = fminf(mn, __shfl_xor(mn, off, 64));
      mx = fmaxf(mx, __shfl_xor(mx, off, 64));
    }
    if (tid == 0) { lohi[0] = mn; lohi[1] = mx; }
  }
  __syncthreads();
  {
    const float lo = lohi[0];
    const float denom = lohi[1] - lo + 1e-5f;
    if (tid < NR) scn[tid] = (scn[tid] - lo) / denom;
  }
  __syncthreads();

  // per-thread serial argmax (threads 0..SPC-1)
  if (tid < SPC) {
    const float* npr = &nl[tid * NR];
    float bv = scn[0] + sg * npr[0];
    int bi = 0;
    for (int r = 1; r < NR; r++) {
      const float v = scn[r] + sg * npr[r];
      if (v > bv) { bv = v; bi = r; }
    }
    atomicAdd(&hist[bi], 1);
  }
  __syncthreads();

  // dense partial-histogram write into workspace: wsp[(bk*NCH+ch)*NR + r]
  if (tid < NR) {
    wsp[(bk * NCH + ch) * NR + tid] = hist[tid];
  }
}

// -------- Kernel 2: weighted strided gather, 4-ki register-blocked ----------
// out[b,c,t, ki*32+a1, j..j+3] = sum_{oi,oj} w[oi*11+oj] * x[.., a1+32*(ki+oi), j+32*oj]
// One block per (b,c,t,p) with p selecting a1 in {2p, 2p+1}; 64 threads =
// 2 a1-halves x 32 column-quads. Each thread computes ALL 4 ki outputs for
// its (a1, j): each staged x float4 is ds_read once and feeds up to 4
// accumulators (r = oi*11+oj ascending per output -> bit-identical to the
// validated per-ki version). Weights live in 31 f32x4 VGPRs (static indices
// after full unroll) -> zero LDS weight broadcasts in the inner loop.
__global__ __launch_bounds__(64, 1) void gather_kernel(
    const void* __restrict__ xv, const void* __restrict__ scorev,
    const int* __restrict__ wsp, const int* __restrict__ group_id,
    void* __restrict__ outv) {
  int blk = blockIdx.x;
  const int p = blk & 15; blk >>= 4;
  const int t = blk % TT; blk /= TT;
  const int c = blk % CC; const int b = blk / CC;
  const int tid = threadIdx.x;

  __shared__ __align__(16) float xs[2 * XSH];  // 50176 B (2 a1-halves)
  __shared__ __align__(16) float scn[124];     // 121 weights + pad

  const bool is_f32 = sniff_is_f32(scorev);
  const int a1base = p * 2;

  // stage the 28 needed x rows {a1base+h + 32g : h in {0,1}, g in [0,14)} as f32
  if (is_f32) {
    const float* xb = (const float*)xv + ((size_t)((b * CC + c) * TT + t)) * (HW * HW);
    for (int i = tid; i < 2 * GG * (HW / 4); i += 64) {
      const int hh = i / (GG * (HW / 4));
      const int rem = i - hh * (GG * (HW / 4));
      const int g = rem / (HW / 4);
      const int c4 = rem - g * (HW / 4);
      *(f32x4*)&xs[hh * XSH + g * HW + c4 * 4] =
          *(const f32x4*)((const float*)xb + (size_t)(a1base + hh + AA * g) * HW + c4 * 4);
    }
  } else {
    const u16* xb = (const u16*)xv + ((size_t)((b * CC + c) * TT + t)) * (HW * HW);
    for (int i = tid; i < 2 * GG * (HW / 8); i += 64) {
      const int hh = i / (GG * (HW / 8));
      const int rem = i - hh * (GG * (HW / 8));
      const int g = rem / (HW / 8);
      const int c8 = rem - g * (HW / 8);
      const uint4 v = *(const uint4*)(xb + (size_t)(a1base + hh + AA * g) * HW + c8 * 8);
      float* d = &xs[hh * XSH + g * HW + c8 * 8];
      f32x4 lo, hi;
      lo[0] = bf2f((u16)(v.x & 0xffffu)); lo[1] = bf2f((u16)(v.x >> 16));
      lo[2] = bf2f((u16)(v.y & 0xffffu)); lo[3] = bf2f((u16)(v.y >> 16));
      hi[0] = bf2f((u16)(v.z & 0xffffu)); hi[1] = bf2f((u16)(v.z >> 16));
      hi[2] = bf2f((u16)(v.w & 0xffffu)); hi[3] = bf2f((u16)(v.w >> 16));
      *(f32x4*)d = lo;
      *(f32x4*)(d + 4) = hi;
    }
  }

  // weights: merge the 25 dense partial histograms for this (b,t)
  {
    const int mybk = b * NKEY + group_id[b * TT + t];
    for (int r = tid; r < NR; r += 64) {
      int acc = 0;
#pragma unroll
      for (int ch = 0; ch < NCH; ch++) acc += wsp[(mybk * NCH + ch) * NR + r];
      scn[r] = (float)acc * (1.0f / NS);
    }
    if (tid < 3) scn[NR + tid] = 0.f;  // pad (never multiplied, keeps loads defined)
  }
  __syncthreads();

  // hoist all 121 weights into registers (31 x f32x4; indices static post-unroll)
  f32x4 w4[31];
#pragma unroll
  for (int q = 0; q < 31; q++) w4[q] = *(const f32x4*)&scn[4 * q];

  const int h = tid >> 5;
  const int j = (tid & 31) * 4;
  const float* xh = &xs[h * XSH];

  f32x4 q0 = 0.f, q1 = 0.f, q2 = 0.f, q3 = 0.f;

#define WV(oi, oj) (w4[((oi) * RR + (oj)) >> 2][((oi) * RR + (oj)) & 3])
#pragma unroll
  for (int g = 0; g < GG; g++) {
#pragma unroll
    for (int oj = 0; oj < RR; oj++) {
      const f32x4 v = *(const f32x4*)(xh + g * HW + j + AA * oj);
      if (g - 0 >= 0 && g - 0 < RR) q0 += WV(g - 0, oj) * v;
      if (g - 1 >= 0 && g - 1 < RR) q1 += WV(g - 1, oj) * v;
      if (g - 2 >= 0 && g - 2 < RR) q2 += WV(g - 2, oj) * v;
      if (g - 3 >= 0 && g - 3 < RR) q3 += WV(g - 3, oj) * v;
    }
  }
#undef WV

  const int a1 = a1base + h;
  const size_t rowbase = (size_t)((b * CC + c) * TT + t) * 128;
  if (is_f32) {
    float* ob = (float*)outv;
    *(f32x4*)&ob[(rowbase + (0 * AA + a1)) * 128 + j] = q0;
    *(f32x4*)&ob[(rowbase + (1 * AA + a1)) * 128 + j] = q1;
    *(f32x4*)&ob[(rowbase + (2 * AA + a1)) * 128 + j] = q2;
    *(f32x4*)&ob[(rowbase + (3 * AA + a1)) * 128 + j] = q3;
  } else {
    u16* ob = (u16*)outv;
    uint2 ov;
    ov.x = (u32)f2bf(q0[0]) | ((u32)f2bf(q0[1]) << 16);
    ov.y = (u32)f2bf(q0[2]) | ((u32)f2bf(q0[3]) << 16);
    *(uint2*)&ob[(rowbase + (0 * AA + a1)) * 128 + j] = ov;
    ov.x = (u32)f2bf(q1[0]) | ((u32)f2bf(q1[1]) << 16);
    ov.y = (u32)f2bf(q1[2]) | ((u32)f2bf(q1[3]) << 16);
    *(uint2*)&ob[(rowbase + (1 * AA + a1)) * 128 + j] = ov;
    ov.x = (u32)f2bf(q2[0]) | ((u32)f2bf(q2[1]) << 16);
    ov.y = (u32)f2bf(q2[2]) | ((u32)f2bf(q2[3]) << 16);
    *(uint2*)&ob[(rowbase + (2 * AA + a1)) * 128 + j] = ov;
    ov.x = (u32)f2bf(q3[0]) | ((u32)f2bf(q3[1]) << 16);
    ov.y = (u32)f2bf(q3[2]) | ((u32)f2bf(q3[3]) << 16);
    *(uint2*)&ob[(rowbase + (3 * AA + a1)) * 128 + j] = ov;
  }
}

extern "C" void kernel_launch(void* const* d_in, const int* in_sizes, int n_in,
                              void* d_out, int out_size, void* d_ws, size_t ws_size,
                              hipStream_t stream) {
  const void* x = d_in[0];         // (2,3,8,448,448)
  const void* score = d_in[1];     // (2,4,196)
  const void* noise = d_in[2];     // (8,500,121) — read-only
  const void* sigma = d_in[3];     // scalar
  const int* group_id = (const int*)d_in[4];  // (2,8) int32
  (void)in_sizes; (void)n_in; (void)out_size; (void)ws_size;

  int* wsp = (int*)d_ws;  // 8*25*121 ints = 48.4 KB of workspace

  hist_part<<<dim3(BB * NKEY * NCH), 128, 0, stream>>>(score, noise, sigma, wsp);
  gather_kernel<<<dim3(BB * CC * TT * (AA / 2)), 64, 0, stream>>>(x, score, wsp,
                                                                  group_id, d_out);
}

// Round 3
// 98.174 us; speedup vs baseline: 1.0715x; 1.0715x over previous
//
#include <hip/hip_runtime.h>

#define BB 2
#define CC 3
#define TT 8
#define HW 448
#define AA 32
#define GG 14      // 448/32
#define RR 11      // 11x11 region grid
#define NR 121
#define NKEY 4
#define NS 500
#define NCH 25     // chunks per bk
#define SPC 20     // samples per chunk (25*20 = 500)

typedef unsigned short u16;
typedef unsigned int u32;
typedef float f32x4 __attribute__((ext_vector_type(4)));

__device__ __forceinline__ float bf2f(u16 u) {
  union { u32 i; float f; } v; v.i = ((u32)u) << 16; return v.f;
}
__device__ __forceinline__ u16 f2bf(float f) {
  union { float f; u32 i; } v; v.f = f;
  u32 u = v.i;
  return (u16)((u + 0x7fffu + ((u >> 16) & 1u)) >> 16);  // round-nearest-even
}

// dtype sniff (validated): score ~ U(0,1); bf16 bit patterns of such values
// lie in {0} U [0x2000, 0x3F80]; f32 mantissa halves are random.
__device__ __forceinline__ bool sniff_is_f32(const void* scorev) {
  const u16* sh16 = (const u16*)scorev;
  bool bf_ok = true;
#pragma unroll
  for (int i = 0; i < 16; i++) {
    const u16 v = sh16[i];
    if (!(v == 0 || (v >= 0x2000 && v <= 0x3F80))) bf_ok = false;
  }
  return !bf_ok;
}

__device__ __forceinline__ float read_sigma(const void* sigmav, bool is_f32) {
  const u32 w0 = *(const u32*)sigmav;
  if (is_f32) { union { u32 i; float f; } v; v.i = w0; return v.f; }
  float sg = bf2f((u16)(w0 & 0xffffu));
  union { u32 i; float f; } v; v.i = w0;
  if (!(sg > -100.f && sg < 100.f) && (v.f > -100.f && v.f < 100.f)) sg = v.f;
  return sg;
}

// -------- Kernel 1: partial histograms, one block per (bk, chunk) -----------
// 200 blocks x 128 threads. Unchanged (validated; ~2-3 us total).
__global__ __launch_bounds__(128) void hist_part(
    const void* __restrict__ scorev, const void* __restrict__ noisev,
    const void* __restrict__ sigmav, int* __restrict__ wsp) {
  const int bk = blockIdx.x / NCH;
  const int ch = blockIdx.x % NCH;
  const int tid = threadIdx.x;

  __shared__ float nl[SPC * NR];  // 9680 B
  __shared__ float scn[NR];
  __shared__ int hist[NR];
  __shared__ float lohi[2];

  const bool is_f32 = sniff_is_f32(scorev);
  const float sg = read_sigma(sigmav, is_f32);

  const size_t chunk_elem = (size_t)(bk * NS + ch * SPC) * NR;

  // stage noise chunk -> LDS (f32)
  if (is_f32) {
    const float* nb = (const float*)noisev + chunk_elem;
    for (int i = tid; i < SPC * NR; i += 128) nl[i] = nb[i];
  } else {
    const u16* nb = (const u16*)noisev + chunk_elem;
    for (int i = tid; i < SPC * NR; i += 128) nl[i] = bf2f(nb[i]);
  }

  // pooled 4x4-mean score -> scn
  if (tid < NR) {
    hist[tid] = 0;
    const int oi = tid / RR, oj = tid - oi * RR;
    float ssum = 0.f;
    if (is_f32) {
      const float* sp = (const float*)scorev + bk * (GG * GG);
#pragma unroll
      for (int ki = 0; ki < 4; ki++)
#pragma unroll
        for (int kj = 0; kj < 4; kj++) ssum += sp[(oi + ki) * GG + (oj + kj)];
    } else {
      const u16* sp = (const u16*)scorev + bk * (GG * GG);
#pragma unroll
      for (int ki = 0; ki < 4; ki++)
#pragma unroll
        for (int kj = 0; kj < 4; kj++) ssum += bf2f(sp[(oi + ki) * GG + (oj + kj)]);
    }
    scn[tid] = ssum * 0.0625f;
  }
  __syncthreads();
  if (tid < 64) {
    float v1 = scn[tid];
    float v2 = (tid + 64 < NR) ? scn[tid + 64] : v1;
    float mn = fminf(v1, v2), mx = fmaxf(v1, v2);
#pragma unroll
    for (int off = 32; off > 0; off >>= 1) {
      mn = fminf(mn, __shfl_xor(mn, off, 64));
      mx = fmaxf(mx, __shfl_xor(mx, off, 64));
    }
    if (tid == 0) { lohi[0] = mn; lohi[1] = mx; }
  }
  __syncthreads();
  {
    const float lo = lohi[0];
    const float denom = lohi[1] - lo + 1e-5f;
    if (tid < NR) scn[tid] = (scn[tid] - lo) / denom;
  }
  __syncthreads();

  // per-thread serial argmax (threads 0..SPC-1)
  if (tid < SPC) {
    const float* npr = &nl[tid * NR];
    float bv = scn[0] + sg * npr[0];
    int bi = 0;
    for (int r = 1; r < NR; r++) {
      const float v = scn[r] + sg * npr[r];
      if (v > bv) { bv = v; bi = r; }
    }
    atomicAdd(&hist[bi], 1);
  }
  __syncthreads();

  // dense partial-histogram write into workspace: wsp[(bk*NCH+ch)*NR + r]
  if (tid < NR) {
    wsp[(bk * NCH + ch) * NR + tid] = hist[tid];
  }
}

// -------- Kernel 2: weighted strided gather, 4-ki blocked, 32 compute lanes -
// out[b,c,t, ki*32+a1, j..j+3] = sum_{oi,oj} w[oi*11+oj] * x[.., a1+32*(ki+oi), j+32*oj]
// One block per (b,c,t,a1), 128 threads (round-1 occupancy shape: 25.5 KB LDS,
// 6 blocks/CU, 2 waves staging). Compute: threads 0..31 each own one column
// quad and produce ALL 4 ki outputs -> 154 ds_read_b128 per block (vs 2x121
// reads + 2x121 broadcasts), weights in 31 f32x4 VGPRs (static indices after
// full unroll). Per-output FMA order is (oi asc, oj asc) == validated order
// -> bit-identical.
__global__ __launch_bounds__(128, 2) void gather_kernel(
    const void* __restrict__ xv, const void* __restrict__ scorev,
    const int* __restrict__ wsp, const int* __restrict__ group_id,
    void* __restrict__ outv) {
  int blk = blockIdx.x;
  const int a1 = blk & (AA - 1); blk >>= 5;
  const int t = blk % TT; blk /= TT;
  const int c = blk % CC; const int b = blk / CC;
  const int tid = threadIdx.x;

  __shared__ __align__(16) float xs[GG][HW];  // 25088 B
  __shared__ __align__(16) float scn[124];    // 121 weights + pad

  const bool is_f32 = sniff_is_f32(scorev);

  // stage the 14 needed x rows {a1+32g} into LDS as f32 (validated round-1 code)
  if (is_f32) {
    const float* xb = (const float*)xv + ((size_t)((b * CC + c) * TT + t)) * (HW * HW);
    for (int i = tid; i < GG * (HW / 4); i += 128) {
      const int g = i / (HW / 4);
      const int c4 = i - g * (HW / 4);
      *(f32x4*)(&xs[g][c4 * 4]) =
          *(const f32x4*)(xb + (size_t)(a1 + AA * g) * HW + c4 * 4);
    }
  } else {
    const u16* xb = (const u16*)xv + ((size_t)((b * CC + c) * TT + t)) * (HW * HW);
    for (int i = tid; i < GG * (HW / 8); i += 128) {
      const int g = i / (HW / 8);
      const int c8 = i - g * (HW / 8);
      const uint4 v = *(const uint4*)(xb + (size_t)(a1 + AA * g) * HW + c8 * 8);
      float* d = &xs[g][c8 * 8];
      d[0] = bf2f((u16)(v.x & 0xffffu)); d[1] = bf2f((u16)(v.x >> 16));
      d[2] = bf2f((u16)(v.y & 0xffffu)); d[3] = bf2f((u16)(v.y >> 16));
      d[4] = bf2f((u16)(v.z & 0xffffu)); d[5] = bf2f((u16)(v.z >> 16));
      d[6] = bf2f((u16)(v.w & 0xffffu)); d[7] = bf2f((u16)(v.w >> 16));
    }
  }

  // weights: merge the 25 dense partial histograms for this (b,t)
  {
    const int mybk = b * NKEY + group_id[b * TT + t];
    for (int r = tid; r < NR; r += 128) {
      int acc = 0;
#pragma unroll
      for (int ch = 0; ch < NCH; ch++) acc += wsp[(mybk * NCH + ch) * NR + r];
      scn[r] = (float)acc * (1.0f / NS);
    }
    if (tid < 3) scn[NR + tid] = 0.f;  // pad (keeps f32x4 loads defined)
  }
  __syncthreads();

  if (tid < 32) {
    // hoist all 121 weights into registers (31 x f32x4; static indices)
    f32x4 w4[31];
#pragma unroll
    for (int q = 0; q < 31; q++) w4[q] = *(const f32x4*)&scn[4 * q];

    const int j = tid * 4;
    f32x4 q0 = 0.f, q1 = 0.f, q2 = 0.f, q3 = 0.f;

#define WV(oi, oj) (w4[((oi) * RR + (oj)) >> 2][((oi) * RR + (oj)) & 3])
#pragma unroll
    for (int g = 0; g < GG; g++) {
#pragma unroll
      for (int oj = 0; oj < RR; oj++) {
        const f32x4 v = *(const f32x4*)(&xs[g][j + AA * oj]);
        if (g - 0 >= 0 && g - 0 < RR) q0 += WV(g - 0, oj) * v;
        if (g - 1 >= 0 && g - 1 < RR) q1 += WV(g - 1, oj) * v;
        if (g - 2 >= 0 && g - 2 < RR) q2 += WV(g - 2, oj) * v;
        if (g - 3 >= 0 && g - 3 < RR) q3 += WV(g - 3, oj) * v;
      }
    }
#undef WV

    const size_t rowbase = (size_t)((b * CC + c) * TT + t) * 128;
    if (is_f32) {
      float* ob = (float*)outv;
      *(f32x4*)&ob[(rowbase + (0 * AA + a1)) * 128 + j] = q0;
      *(f32x4*)&ob[(rowbase + (1 * AA + a1)) * 128 + j] = q1;
      *(f32x4*)&ob[(rowbase + (2 * AA + a1)) * 128 + j] = q2;
      *(f32x4*)&ob[(rowbase + (3 * AA + a1)) * 128 + j] = q3;
    } else {
      u16* ob = (u16*)outv;
      uint2 ov;
      ov.x = (u32)f2bf(q0[0]) | ((u32)f2bf(q0[1]) << 16);
      ov.y = (u32)f2bf(q0[2]) | ((u32)f2bf(q0[3]) << 16);
      *(uint2*)&ob[(rowbase + (0 * AA + a1)) * 128 + j] = ov;
      ov.x = (u32)f2bf(q1[0]) | ((u32)f2bf(q1[1]) << 16);
      ov.y = (u32)f2bf(q1[2]) | ((u32)f2bf(q1[3]) << 16);
      *(uint2*)&ob[(rowbase + (1 * AA + a1)) * 128 + j] = ov;
      ov.x = (u32)f2bf(q2[0]) | ((u32)f2bf(q2[1]) << 16);
      ov.y = (u32)f2bf(q2[2]) | ((u32)f2bf(q2[3]) << 16);
      *(uint2*)&ob[(rowbase + (2 * AA + a1)) * 128 + j] = ov;
      ov.x = (u32)f2bf(q3[0]) | ((u32)f2bf(q3[1]) << 16);
      ov.y = (u32)f2bf(q3[2]) | ((u32)f2bf(q3[3]) << 16);
      *(uint2*)&ob[(rowbase + (3 * AA + a1)) * 128 + j] = ov;
    }
  }
}

extern "C" void kernel_launch(void* const* d_in, const int* in_sizes, int n_in,
                              void* d_out, int out_size, void* d_ws, size_t ws_size,
                              hipStream_t stream) {
  const void* x = d_in[0];         // (2,3,8,448,448)
  const void* score = d_in[1];     // (2,4,196)
  const void* noise = d_in[2];     // (8,500,121) — read-only
  const void* sigma = d_in[3];     // scalar
  const int* group_id = (const int*)d_in[4];  // (2,8) int32
  (void)in_sizes; (void)n_in; (void)out_size; (void)ws_size;

  int* wsp = (int*)d_ws;  // 8*25*121 ints = 48.4 KB of workspace

  hist_part<<<dim3(BB * NKEY * NCH), 128, 0, stream>>>(score, noise, sigma, wsp);
  gather_kernel<<<dim3(BB * CC * TT * AA), 128, 0, stream>>>(x, score, wsp,
                                                             group_id, d_out);
}